// Round 8
// baseline (135.527 us; speedup 1.0000x reference)
//
#include <hip/hip_runtime.h>
#include <hip/hip_bf16.h>

typedef __attribute__((ext_vector_type(8))) short short8;
typedef __attribute__((ext_vector_type(16))) float f32x16;
typedef __fp16 h2 __attribute__((ext_vector_type(2)));
typedef unsigned short ushort_t;

#define DEVFN static __device__ __forceinline__
#define MFMA32 __builtin_amdgcn_mfma_f32_32x32x16_bf16

DEVFN float bf2f(unsigned short u){
  union { unsigned int i; float f; } v; v.i = ((unsigned int)u) << 16; return v.f;
}
DEVFN unsigned short f2bf(float f){
  unsigned int u = __float_as_uint(f);
  unsigned int r = u + 0x7FFFu + ((u >> 16) & 1u);
  return (unsigned short)(r >> 16);
}
DEVFN unsigned int pkbf(float lo, float hi){
  __hip_bfloat162 h = __float22bfloat162_rn(make_float2(lo, hi));
  return *reinterpret_cast<unsigned int*>(&h);
}
DEVFN h2 pkrtz(float a, float b){ return __builtin_amdgcn_cvt_pkrtz(a, b); }
DEVFN h2 u2h(unsigned int u){ union { unsigned int u; h2 h; } v; v.u = u; return v.h; }
#if __has_builtin(__builtin_amdgcn_fdot2)
DEVFN float fdot2(h2 a, h2 b, float c){ return __builtin_amdgcn_fdot2(a, b, c, false); }
#else
DEVFN float fdot2(h2 a, h2 b, float c){ return c + (float)a[0]*(float)b[0] + (float)a[1]*(float)b[1]; }
#endif
DEVFN float tanh_fast(float x){
  float t = __builtin_amdgcn_exp2f(x * 2.885390081777926815f);
  return 1.0f - 2.0f * __builtin_amdgcn_rcpf(t + 1.0f);
}
// shared A/B K-slot mapping for 32x32x16 MFMA fragments
DEVFN int kmap(int h, int j){ return 4*h + (j & 3) + 8*(j >> 2); }

// ---------------- weight bake ----------------
// wfrag (hw): ((f*4 + gq)*2 + nh)*3072 + (l*2 + nt)*512 + lane*8 + j
//   n = nh*64 + nt*32 + (lane&31) ; g(j) = gq*16 + kmap(lane>>5, j)
__global__ void bake_w0(const float* __restrict__ wx0, const float* __restrict__ wy0,
                        ushort_t* __restrict__ wfrag){
  int slot = blockIdx.x * 256 + threadIdx.x;      // < 196608
  int lane = slot & 63;
  int q = slot >> 6;            // < 3072
  int blk = q % 6; int q2 = q / 6;
  int l = blk >> 1, nt = blk & 1;
  int nh = q2 & 1; int gq = (q2 >> 1) & 3; int f = q2 >> 3;
  int h = lane >> 5;
  int k = nt*32 + (lane & 31);
  const float* w = nh ? wy0 : wx0;
  unsigned int pk[4];
#pragma unroll
  for (int jj = 0; jj < 4; ++jj){
    int g0 = gq*16 + kmap(h, 2*jj);
    int g1 = gq*16 + kmap(h, 2*jj + 1);
    unsigned int b0 = f2bf(w[((k*64 + f)*64 + g0)*3 + l]);
    unsigned int b1 = f2bf(w[((k*64 + f)*64 + g1)*3 + l]);
    pk[jj] = b0 | (b1 << 16);
  }
  *reinterpret_cast<uint4*>(wfrag + (size_t)slot * 8) = make_uint4(pk[0], pk[1], pk[2], pk[3]);
}

__global__ void bake_wh(const float* __restrict__ wxh, const float* __restrict__ wyh,
                        ushort_t* __restrict__ whfrag){
  int slot = blockIdx.x * 256 + threadIdx.x;      // < 2048
  int lane = slot & 63;
  int q = slot >> 6;
  int nt = q & 1; q >>= 1;
  int c  = q & 3; q >>= 2;
  int path = q & 1; int layer = q >> 1;
  const float* w = path ? wyh : wxh;
  int n = nt*32 + (lane & 31);
  int h = lane >> 5;
  unsigned int pk[4];
#pragma unroll
  for (int jj = 0; jj < 4; ++jj){
    int k0 = c*16 + kmap(h, 2*jj);
    int k1 = c*16 + kmap(h, 2*jj + 1);
    unsigned int b0 = f2bf(w[layer*4096 + k0*64 + n]);
    unsigned int b1 = f2bf(w[layer*4096 + k1*64 + n]);
    pk[jj] = b0 | (b1 << 16);
  }
  *reinterpret_cast<uint4*>(whfrag + (size_t)slot * 8) = make_uint4(pk[0], pk[1], pk[2], pk[3]);
}

__global__ void bake_wf(const float* __restrict__ wxf, const float* __restrict__ wyf,
                        ushort_t* __restrict__ wffrag){
  int slot = blockIdx.x * 256 + threadIdx.x;      // < 3072
  int lane = slot & 63;
  int q = slot >> 6;            // < 48
  int ntf = q % 6;
  int q2 = q / 6;
  int c = q2 & 3; int path = q2 >> 2;
  const float* w = path ? wyf : wxf;
  int n = ntf*32 + (lane & 31);
  int lw = n >> 6, fw = n & 63;
  int h = lane >> 5;
  unsigned int pk[4];
#pragma unroll
  for (int jj = 0; jj < 4; ++jj){
    int k0 = c*16 + kmap(h, 2*jj);
    int k1 = c*16 + kmap(h, 2*jj + 1);
    unsigned int b0 = f2bf(w[(lw*64 + fw)*64 + k0]);
    unsigned int b1 = f2bf(w[(lw*64 + fw)*64 + k1]);
    pk[jj] = b0 | (b1 << 16);
  }
  *reinterpret_cast<uint4*>(wffrag + (size_t)slot * 8) = make_uint4(pk[0], pk[1], pk[2], pk[3]);
}

// y -> padded f16 rows of 16 halves (32B): y2h[p][f][16] = (s0..s8, 0 x7)
__global__ void bake_y(const float* __restrict__ y, ushort_t* __restrict__ y2h){
  int idx = blockIdx.x * 256 + threadIdx.x;       // dword index < 4,194,304
  int d = idx & 7; int pf = idx >> 3;
  const float* src = y + (size_t)pf * 9;
  int s0 = d*2, s1 = d*2 + 1;
  float v0 = (s0 < 9) ? src[s0] : 0.f;
  float v1 = (s1 < 9) ? src[s1] : 0.f;
  h2 pk = pkrtz(v0, v1);
  reinterpret_cast<unsigned int*>(y2h)[(size_t)pf*8 + d] =
      *reinterpret_cast<unsigned int*>(&pk);
}

// ---------------- main fused GEMM (barrier-free; small per-wave state) ----------------
// Grid 512 = Mblk(256, 32 pts) x nh(2); WG 256 thr = 4 waves = gq quarters.
// Wave: 1 m-tile (32 pts) x 2 n-tiles x its gq K-quarter, all 64 f.
// Live regs/wave: xg 40 + B ping-pong 48 + Y 10 + addr/temps ~25 = ~120 VGPR
// + 32 AGPR acc -> fits the 128-VGPR cap rounds 5-7 proved immovable.
// gq-reduction in-WG (padded LDS, 4 barriers at end) -> mix is complete.
struct BSet { uint4 b[6]; };
struct YSet { uint4 q; unsigned int d; };
union U4 { uint4 u; short8 s; };

__global__ __launch_bounds__(256)
void gemm8(const float* __restrict__ x, const float* __restrict__ y,
           const ushort_t* __restrict__ y2h, const ushort_t* __restrict__ wfrag,
           float* __restrict__ mix){
  __shared__ float red[2][64][33];

  const int bid = blockIdx.x;
  const int id = (bid & 7)*64 + (bid >> 3);       // XCD-chunked bijection (512 = 8*64)
  const int nh = id & 1, mb = id >> 1;
  const int pbase = mb * 32;

  const int t = threadIdx.x, lane = t & 63, gq = t >> 6;
  const int h = lane >> 5, pr = lane & 31;
  const int p = pbase + pr;

  // ---- xg init: 8 g of this gq quarter, packed h2 pairs (s0,s1)(s2,s3)(s4,s5)(s6,s7)(s8,0)
  h2 xg[8][5];
#pragma unroll
  for (int j = 0; j < 8; ++j){
    const int g = gq*16 + kmap(h, j);
    const float* xp = x + (size_t)p*576 + g*9;
    const float* yp = y + (size_t)p*576 + g*9;
    float x1 = xp[1], x2 = xp[2], x3 = xp[3];
    float y0 = yp[0], y1 = yp[1], y2 = yp[2], y3 = yp[3];
    float gate = (x2*y3 - x3*y2)*y0 + (x3*y1 - x1*y3)*y1 + (x1*y2 - x2*y1)*y2;
    xg[j][0] = pkrtz(xp[0]*gate, x1*gate);
    xg[j][1] = pkrtz(x2*gate, x3*gate);
    xg[j][2] = pkrtz(xp[4]*gate, xp[5]*gate);
    xg[j][3] = pkrtz(xp[6]*gate, xp[7]*gate);
    xg[j][4] = pkrtz(xp[8]*gate, 0.f);
  }

  f32x16 acc0, acc1;
#pragma unroll
  for (int e = 0; e < 16; ++e){ acc0[e] = 0.f; acc1[e] = 0.f; }

  const ushort_t* wt = wfrag + (size_t)(gq*2 + nh)*3072 + (size_t)lane*8;
  const ushort_t* yrow = y2h + (size_t)p * 1024;   // 64 f x 16 halves

  auto ldB = [&](int f, BSet& B){
    const ushort_t* p0 = wt + (size_t)f * 24576;
#pragma unroll
    for (int i = 0; i < 6; ++i) B.b[i] = *reinterpret_cast<const uint4*>(p0 + i*512);
  };
  auto ldY = [&](int f, YSet& Y){
    const ushort_t* r = yrow + f*16;
    Y.q = *reinterpret_cast<const uint4*>(r);
    Y.d = *reinterpret_cast<const unsigned int*>(r + 8);
  };
  auto agen_mfma = [&](const YSet& Y, const BSet& B){
    h2 y0m = u2h(Y.q.x & 0xFFFFu);
    h2 y1m = u2h(Y.q.x & 0xFFFF0000u);
    h2 y23 = u2h(Y.q.y), y45 = u2h(Y.q.z), y67 = u2h(Y.q.w), y8p = u2h(Y.d);
    float a0[8], a1[8], a2[8];
#pragma unroll
    for (int j = 0; j < 8; ++j){
      a0[j] = fdot2(xg[j][0], y0m, 0.f);
      a1[j] = fdot2(xg[j][1], y23, fdot2(xg[j][0], y1m, 0.f));
      a2[j] = fdot2(xg[j][4], y8p, fdot2(xg[j][3], y67, fdot2(xg[j][2], y45, 0.f)));
    }
    U4 fA0, fA1, fA2;
    fA0.u = make_uint4(pkbf(a0[0],a0[1]), pkbf(a0[2],a0[3]), pkbf(a0[4],a0[5]), pkbf(a0[6],a0[7]));
    fA1.u = make_uint4(pkbf(a1[0],a1[1]), pkbf(a1[2],a1[3]), pkbf(a1[4],a1[5]), pkbf(a1[6],a1[7]));
    fA2.u = make_uint4(pkbf(a2[0],a2[1]), pkbf(a2[2],a2[3]), pkbf(a2[4],a2[5]), pkbf(a2[6],a2[7]));
    U4 b0, b1, b2, b3, b4, b5;
    b0.u = B.b[0]; b1.u = B.b[1]; b2.u = B.b[2];
    b3.u = B.b[3]; b4.u = B.b[4]; b5.u = B.b[5];
    acc0 = MFMA32(fA0.s, b0.s, acc0, 0, 0, 0);
    acc1 = MFMA32(fA0.s, b1.s, acc1, 0, 0, 0);
    acc0 = MFMA32(fA1.s, b2.s, acc0, 0, 0, 0);
    acc1 = MFMA32(fA1.s, b3.s, acc1, 0, 0, 0);
    acc0 = MFMA32(fA2.s, b4.s, acc0, 0, 0, 0);
    acc1 = MFMA32(fA2.s, b5.s, acc1, 0, 0, 0);
  };

  BSet Ba, Bb; YSet Ya, Yb;
  ldB(0, Ba); ldY(0, Ya);
  ldB(1, Bb); ldY(1, Yb);

#pragma unroll 1
  for (int s = 0; s < 64; s += 2){
    agen_mfma(Ya, Ba);
    const int s2 = (s + 2 < 64) ? s + 2 : 63;
    ldB(s2, Ba); ldY(s2, Ya);
    agen_mfma(Yb, Bb);
    const int s3 = (s + 3 < 64) ? s + 3 : 63;
    ldB(s3, Bb); ldY(s3, Yb);
  }

  // ---- in-WG reduction over gq (padded LDS, conflict-free) ----
  if (gq >= 2){
#pragma unroll
    for (int e = 0; e < 16; ++e){
      red[gq-2][lane][e]      = acc0[e];
      red[gq-2][lane][16 + e] = acc1[e];
    }
  }
  __syncthreads();
  if (gq < 2){
#pragma unroll
    for (int e = 0; e < 16; ++e){
      acc0[e] += red[gq][lane][e];
      acc1[e] += red[gq][lane][16 + e];
    }
  }
  __syncthreads();
  if (gq == 1){
#pragma unroll
    for (int e = 0; e < 16; ++e){
      red[0][lane][e]      = acc0[e];
      red[0][lane][16 + e] = acc1[e];
    }
  }
  __syncthreads();
  if (gq == 0){
#pragma unroll
    for (int e = 0; e < 16; ++e){
      float v0 = acc0[e] + red[0][lane][e];
      float v1 = acc1[e] + red[0][lane][16 + e];
      int rowm = (e & 3) + 8*(e >> 2) + 4*h;
      float* d = mix + (size_t)(pbase + rowm)*128 + nh*64 + pr;
      d[0]  = v0;
      d[32] = v1;
    }
  }
}

// ---------------- MLP + final einsum + epilogue ----------------
__global__ __launch_bounds__(256, 1)
void mlp_final(const float* __restrict__ x, const float* __restrict__ y,
               const ushort_t* __restrict__ whfrag,
               const ushort_t* __restrict__ wffrag,
               const float* __restrict__ mix, float* __restrict__ out){
  extern __shared__ char ldsm[];
  ushort_t* hw = (ushort_t*)ldsm;
  const int t = threadIdx.x;
  const long pbase = (long)blockIdx.x * 32;

  {  // load mix -> act buf0 (bf16)
    int p = t >> 3, n0 = (t & 7) * 16;
    const float* src = mix + (pbase + p)*128 + n0;
    int path = n0 >> 6, nn = n0 & 63;
    ushort_t* dst = hw + (path*2)*2176 + p*68 + nn;
#pragma unroll
    for (int q2 = 0; q2 < 16; ++q2) dst[q2] = f2bf(src[q2]);
  }
  __syncthreads();

  const int w = t >> 6, lane = t & 63;
  const int path = w >> 1, ntw = w & 1;
  const int prow = lane & 31, h = lane >> 5;
  int cur = 0;

#pragma unroll
  for (int layer = 0; layer < 2; ++layer){
    const ushort_t* act = hw + (path*2 + cur)*2176;
    f32x16 acc;
#pragma unroll
    for (int r = 0; r < 16; ++r) acc[r] = 0.f;
#pragma unroll
    for (int c = 0; c < 4; ++c){
      int ab = prow*68 + c*16 + 4*h;
      ushort4 lo = *(const ushort4*)&act[ab];
      ushort4 hi = *(const ushort4*)&act[ab + 8];
      short8 av; av[0]=lo.x; av[1]=lo.y; av[2]=lo.z; av[3]=lo.w;
      av[4]=hi.x; av[5]=hi.y; av[6]=hi.z; av[7]=hi.w;
      short8 bv = *(const short8*)(whfrag + ((((layer*2 + path)*4 + c)*2 + ntw)*512 + lane*8));
      acc = MFMA32(av, bv, acc, 0, 0, 0);
    }
    ushort_t* nact = hw + (path*2 + (cur ^ 1))*2176;
#pragma unroll
    for (int r = 0; r < 16; ++r){
      int p = (r & 3) + 8*(r >> 2) + 4*h;
      nact[p*68 + ntw*32 + prow] = f2bf(tanh_fast(acc[r]));
    }
    cur ^= 1;
    __syncthreads();
  }

  {  // final einsum: o[p][n=l*64+f], N=192 -> each wave 3 n-tiles
    const ushort_t* act = hw + (path*2 + cur)*2176;
    ushort_t* ob = hw + 8704 + path*6272;
#pragma unroll
    for (int e = 0; e < 3; ++e){
      int ntf = ntw*3 + e;
      f32x16 acc;
#pragma unroll
      for (int r = 0; r < 16; ++r) acc[r] = 0.f;
#pragma unroll
      for (int c = 0; c < 4; ++c){
        int ab = prow*68 + c*16 + 4*h;
        ushort4 lo = *(const ushort4*)&act[ab];
        ushort4 hi = *(const ushort4*)&act[ab + 8];
        short8 av; av[0]=lo.x; av[1]=lo.y; av[2]=lo.z; av[3]=lo.w;
        av[4]=hi.x; av[5]=hi.y; av[6]=hi.z; av[7]=hi.w;
        short8 bv = *(const short8*)(wffrag + (((path*4 + c)*6 + ntf)*512 + lane*8));
        acc = MFMA32(av, bv, acc, 0, 0, 0);
      }
#pragma unroll
      for (int r = 0; r < 16; ++r){
        int p = (r & 3) + 8*(r >> 2) + 4*h;
        ob[p*196 + ntf*32 + prow] = f2bf(tanh_fast(acc[r]));
      }
    }
  }
  __syncthreads();

  const ushort_t* oxb = hw + 8704;
  const ushort_t* oyb = hw + 8704 + 6272;
#pragma unroll 1
  for (int rep = 0; rep < 8; ++rep){
    int idx = t + rep*256;
    int p = idx >> 6, fq = idx & 63;
    const float* xr = x + ((pbase + p)*64 + fq)*9;
    const float* yr = y + ((pbase + p)*64 + fq)*9;
    float xv[9], yv[9];
#pragma unroll
    for (int s = 0; s < 9; ++s){ xv[s] = xr[s]; yv[s] = yr[s]; }
    float c0 = xv[2]*yv[3] - xv[3]*yv[2];
    float c1 = xv[3]*yv[1] - xv[1]*yv[3];
    float c2 = xv[1]*yv[2] - xv[2]*yv[1];
    float gate = c0*yv[0] + c1*yv[1] + c2*yv[2];
    float ox0 = bf2f(oxb[p*196 + fq]);
    float ox1 = bf2f(oxb[p*196 + 64 + fq]);
    float ox2 = bf2f(oxb[p*196 + 128 + fq]);
    float oy0 = bf2f(oyb[p*196 + fq]);
    float oy1 = bf2f(oyb[p*196 + 64 + fq]);
    float oy2 = bf2f(oyb[p*196 + 128 + fq]);
    float* orow = out + ((pbase + p)*64 + fq)*9;
    orow[0] = ox0*xv[0]*gate + oy0*yv[0];
#pragma unroll
    for (int s = 1; s < 4; ++s) orow[s] = ox1*xv[s]*gate + oy1*yv[s];
#pragma unroll
    for (int s = 4; s < 9; ++s) orow[s] = ox2*xv[s]*gate + oy2*yv[s];
  }
}

extern "C" void kernel_launch(void* const* d_in, const int* in_sizes, int n_in,
                              void* d_out, int out_size, void* d_ws, size_t ws_size,
                              hipStream_t stream){
  (void)in_sizes; (void)n_in; (void)out_size; (void)ws_size;
  const float* x   = (const float*)d_in[0];
  const float* y   = (const float*)d_in[1];
  const float* wx0 = (const float*)d_in[2];
  const float* wy0 = (const float*)d_in[3];
  const float* wxh = (const float*)d_in[4];
  const float* wyh = (const float*)d_in[5];
  const float* wxf = (const float*)d_in[6];
  const float* wyf = (const float*)d_in[7];
  float* out = (float*)d_out;
  char* ws = (char*)d_ws;
  ushort_t* wfrag  = (ushort_t*)(ws);              //  3,145,728 B
  ushort_t* whfrag = (ushort_t*)(ws + 3145728);    //     32,768 B
  ushort_t* wffrag = (ushort_t*)(ws + 3178496);    //     49,152 B
  ushort_t* y2h    = (ushort_t*)(ws + 3227648);    // 16,777,216 B
  float* mix       = (float*)(ws + 20004864);      //  4,194,304 B

  (void)hipFuncSetAttribute((const void*)mlp_final,
        hipFuncAttributeMaxDynamicSharedMemorySize, 43520);

  hipLaunchKernelGGL(bake_w0, dim3(768),   dim3(256), 0, stream, wx0, wy0, wfrag);
  hipLaunchKernelGGL(bake_wh, dim3(8),     dim3(256), 0, stream, wxh, wyh, whfrag);
  hipLaunchKernelGGL(bake_wf, dim3(12),    dim3(256), 0, stream, wxf, wyf, wffrag);
  hipLaunchKernelGGL(bake_y,  dim3(16384), dim3(256), 0, stream, y, y2h);
  hipLaunchKernelGGL(gemm8,   dim3(512),   dim3(256), 0, stream, x, y, y2h, wfrag, mix);
  hipLaunchKernelGGL(mlp_final, dim3(256), dim3(256), 42496, stream, x, y, whfrag, wffrag, mix, out);
}

// Round 9
// 91.699 us; speedup vs baseline: 1.4780x; 1.4780x over previous
//
#include <hip/hip_runtime.h>
#include <hip/hip_bf16.h>

typedef __attribute__((ext_vector_type(8))) short short8;
typedef __attribute__((ext_vector_type(16))) float f32x16;
typedef __fp16 h2 __attribute__((ext_vector_type(2)));
typedef unsigned short ushort_t;

#define DEVFN static __device__ __forceinline__
#define MFMA32 __builtin_amdgcn_mfma_f32_32x32x16_bf16

DEVFN float bf2f(unsigned short u){
  union { unsigned int i; float f; } v; v.i = ((unsigned int)u) << 16; return v.f;
}
DEVFN unsigned short f2bf(float f){
  unsigned int u = __float_as_uint(f);
  unsigned int r = u + 0x7FFFu + ((u >> 16) & 1u);
  return (unsigned short)(r >> 16);
}
DEVFN unsigned int pkbf(float lo, float hi){
  __hip_bfloat162 h = __float22bfloat162_rn(make_float2(lo, hi));
  return *reinterpret_cast<unsigned int*>(&h);
}
DEVFN h2 pkrtz(float a, float b){ return __builtin_amdgcn_cvt_pkrtz(a, b); }
DEVFN h2 u2h(unsigned int u){ union { unsigned int u; h2 h; } v; v.u = u; return v.h; }
#if __has_builtin(__builtin_amdgcn_fdot2)
DEVFN float fdot2(h2 a, h2 b, float c){ return __builtin_amdgcn_fdot2(a, b, c, false); }
#else
DEVFN float fdot2(h2 a, h2 b, float c){ return c + (float)a[0]*(float)b[0] + (float)a[1]*(float)b[1]; }
#endif
DEVFN float tanh_fast(float x){
  float t = __builtin_amdgcn_exp2f(x * 2.885390081777926815f);
  return 1.0f - 2.0f * __builtin_amdgcn_rcpf(t + 1.0f);
}
// shared A/B K-slot mapping for 32x32x16 MFMA fragments
DEVFN int kmap(int h, int j){ return 4*h + (j & 3) + 8*(j >> 2); }

// ---------------- weight bake ----------------
// wfrag (hw): ((f*4 + gq)*2 + nh)*3072 + (l*2 + nt)*512 + lane*8 + j
//   n = nh*64 + nt*32 + (lane&31) ; g(j) = gq*16 + kmap(lane>>5, j)
__global__ void bake_w0(const float* __restrict__ wx0, const float* __restrict__ wy0,
                        ushort_t* __restrict__ wfrag){
  int slot = blockIdx.x * 256 + threadIdx.x;      // < 196608
  int lane = slot & 63;
  int q = slot >> 6;            // < 3072
  int blk = q % 6; int q2 = q / 6;
  int l = blk >> 1, nt = blk & 1;
  int nh = q2 & 1; int gq = (q2 >> 1) & 3; int f = q2 >> 3;
  int h = lane >> 5;
  int k = nt*32 + (lane & 31);
  const float* w = nh ? wy0 : wx0;
  unsigned int pk[4];
#pragma unroll
  for (int jj = 0; jj < 4; ++jj){
    int g0 = gq*16 + kmap(h, 2*jj);
    int g1 = gq*16 + kmap(h, 2*jj + 1);
    unsigned int b0 = f2bf(w[((k*64 + f)*64 + g0)*3 + l]);
    unsigned int b1 = f2bf(w[((k*64 + f)*64 + g1)*3 + l]);
    pk[jj] = b0 | (b1 << 16);
  }
  *reinterpret_cast<uint4*>(wfrag + (size_t)slot * 8) = make_uint4(pk[0], pk[1], pk[2], pk[3]);
}

__global__ void bake_wh(const float* __restrict__ wxh, const float* __restrict__ wyh,
                        ushort_t* __restrict__ whfrag){
  int slot = blockIdx.x * 256 + threadIdx.x;      // < 2048
  int lane = slot & 63;
  int q = slot >> 6;
  int nt = q & 1; q >>= 1;
  int c  = q & 3; q >>= 2;
  int path = q & 1; int layer = q >> 1;
  const float* w = path ? wyh : wxh;
  int n = nt*32 + (lane & 31);
  int h = lane >> 5;
  unsigned int pk[4];
#pragma unroll
  for (int jj = 0; jj < 4; ++jj){
    int k0 = c*16 + kmap(h, 2*jj);
    int k1 = c*16 + kmap(h, 2*jj + 1);
    unsigned int b0 = f2bf(w[layer*4096 + k0*64 + n]);
    unsigned int b1 = f2bf(w[layer*4096 + k1*64 + n]);
    pk[jj] = b0 | (b1 << 16);
  }
  *reinterpret_cast<uint4*>(whfrag + (size_t)slot * 8) = make_uint4(pk[0], pk[1], pk[2], pk[3]);
}

__global__ void bake_wf(const float* __restrict__ wxf, const float* __restrict__ wyf,
                        ushort_t* __restrict__ wffrag){
  int slot = blockIdx.x * 256 + threadIdx.x;      // < 3072
  int lane = slot & 63;
  int q = slot >> 6;            // < 48
  int ntf = q % 6;
  int q2 = q / 6;
  int c = q2 & 3; int path = q2 >> 2;
  const float* w = path ? wyf : wxf;
  int n = ntf*32 + (lane & 31);
  int lw = n >> 6, fw = n & 63;
  int h = lane >> 5;
  unsigned int pk[4];
#pragma unroll
  for (int jj = 0; jj < 4; ++jj){
    int k0 = c*16 + kmap(h, 2*jj);
    int k1 = c*16 + kmap(h, 2*jj + 1);
    unsigned int b0 = f2bf(w[(lw*64 + fw)*64 + k0]);
    unsigned int b1 = f2bf(w[(lw*64 + fw)*64 + k1]);
    pk[jj] = b0 | (b1 << 16);
  }
  *reinterpret_cast<uint4*>(wffrag + (size_t)slot * 8) = make_uint4(pk[0], pk[1], pk[2], pk[3]);
}

// ---------------- main fused GEMM (coalesced-only VMEM) ----------------
// Grid 512 = Mblk(256, 32 pts) x nh(2); WG 256 thr = 4 waves = gq quarters.
// LDS: YH f16 [32 p][325 dwords] @0 (41600 B) ; Xf f32 [32 p][290] @41600 (37120 B)
//      red [2][64][33] aliases Xf after prologue. Total 78720 B -> 2 WG/CU.
// All global loads coalesced float4/dwordx4; main-loop Y via LDS (TA-gather fix).
struct BSet { uint4 b[6]; };
union U4 { uint4 u; short8 s; };

__global__ __launch_bounds__(256)
void gemm9(const float* __restrict__ x, const float* __restrict__ y,
           const ushort_t* __restrict__ wfrag, float* __restrict__ mix){
  extern __shared__ char lds[];
  unsigned int* YHd = (unsigned int*)lds;                 // [32][325] dwords
  ushort_t* YHh = (ushort_t*)lds;
  float* Xf = (float*)(lds + 41600);                      // [32][290] f32
  float (*red)[64][33] = (float (*)[64][33])(lds + 41600);

  const int bid = blockIdx.x;
  const int id = (bid & 7)*64 + (bid >> 3);               // XCD-chunked bijection
  const int nh = id & 1, mb = id >> 1;
  const int pbase = mb * 32;

  const int t = threadIdx.x, lane = t & 63, gq = t >> 6;
  const int h = lane >> 5, pr = lane & 31;

  const float* xb = x + (size_t)pbase * 576;
  const float* yb = y + (size_t)pbase * 576;

  // ---- 0a: stage y as f16 (full) + x half0 (f32), all coalesced ----
#pragma unroll
  for (int c = 0; c < 18; ++c){
    int q = t + c*256;                 // < 4608
    int p = q / 144, off = (q - p*144) * 4;
    float4 v = *(const float4*)(yb + p*576 + off);
#pragma unroll
    for (int i = 0; i < 4; ++i){
      int flat = off + i;
      int f = flat / 9, s = flat - f*9;
      float vv = (i==0) ? v.x : (i==1) ? v.y : (i==2) ? v.z : v.w;
      union { __fp16 hf; ushort_t u; } cv; cv.hf = (__fp16)vv;
      YHh[p*650 + f*10 + s] = cv.u;
    }
  }
#pragma unroll
  for (int c = 0; c < 9; ++c){
    int q = t + c*256;                 // < 2304
    int p = q / 72, off = (q - p*72) * 4;
    float4 v = *(const float4*)(xb + p*576 + off);       // g-half 0
    float* dst = Xf + p*290 + off;
    dst[0] = v.x; dst[1] = v.y; dst[2] = v.z; dst[3] = v.w;
  }
  __syncthreads();

  h2 xg[8][5];
  auto compute_xg = [&](int hf){
#pragma unroll
    for (int j = 0; j < 8; ++j){
      int gl = (gq & 1)*16 + kmap(h, j);     // g within half
      int gg = hf*32 + gl;                   // global g (= feature idx in YH)
      const float* xp = Xf + pr*290 + gl*9;
      unsigned int yd0 = YHd[pr*325 + gg*5 + 0];
      unsigned int yd1 = YHd[pr*325 + gg*5 + 1];
      h2 y01 = u2h(yd0), y23v = u2h(yd1);
      float y0 = (float)y01[0], y1 = (float)y01[1];
      float y2 = (float)y23v[0], y3 = (float)y23v[1];
      float x1 = xp[1], x2 = xp[2], x3 = xp[3];
      float gate = (x2*y3 - x3*y2)*y0 + (x3*y1 - x1*y3)*y1 + (x1*y2 - x2*y1)*y2;
      xg[j][0] = pkrtz(xp[0]*gate, x1*gate);
      xg[j][1] = pkrtz(x2*gate, x3*gate);
      xg[j][2] = pkrtz(xp[4]*gate, xp[5]*gate);
      xg[j][3] = pkrtz(xp[6]*gate, xp[7]*gate);
      xg[j][4] = pkrtz(xp[8]*gate, 0.f);
    }
  };
  if (gq < 2) compute_xg(0);
  __syncthreads();
  // ---- 0c: x half1 ----
#pragma unroll
  for (int c = 0; c < 9; ++c){
    int q = t + c*256;
    int p = q / 72, off = (q - p*72) * 4;
    float4 v = *(const float4*)(xb + p*576 + 288 + off);  // g-half 1
    float* dst = Xf + p*290 + off;
    dst[0] = v.x; dst[1] = v.y; dst[2] = v.z; dst[3] = v.w;
  }
  __syncthreads();
  if (gq >= 2) compute_xg(1);
  __syncthreads();

  // ---- main loop: barrier-free, coalesced B stream + LDS Y ----
  f32x16 acc0, acc1;
#pragma unroll
  for (int e = 0; e < 16; ++e){ acc0[e] = 0.f; acc1[e] = 0.f; }

  const ushort_t* wt = wfrag + (size_t)(gq*2 + nh)*3072 + (size_t)lane*8;
  const unsigned int* yrow = YHd + pr*325;

  auto ldB = [&](int f, BSet& B){
    const ushort_t* p0 = wt + (size_t)f * 24576;
#pragma unroll
    for (int i = 0; i < 6; ++i) B.b[i] = *reinterpret_cast<const uint4*>(p0 + i*512);
  };
  auto ldYh = [&](int f, unsigned int* Yr){
#pragma unroll
    for (int d = 0; d < 5; ++d) Yr[d] = yrow[f*5 + d];
  };
  auto agen_mfma = [&](const unsigned int* Yr, const BSet& B){
    h2 y0m = u2h(Yr[0] & 0xFFFFu);
    h2 y1m = u2h(Yr[0] & 0xFFFF0000u);
    h2 y23 = u2h(Yr[1]), y45 = u2h(Yr[2]), y67 = u2h(Yr[3]);
    h2 y8p = u2h(Yr[4] & 0xFFFFu);
    float a0[8], a1[8], a2[8];
#pragma unroll
    for (int j = 0; j < 8; ++j){
      a0[j] = fdot2(xg[j][0], y0m, 0.f);
      a1[j] = fdot2(xg[j][1], y23, fdot2(xg[j][0], y1m, 0.f));
      a2[j] = fdot2(xg[j][4], y8p, fdot2(xg[j][3], y67, fdot2(xg[j][2], y45, 0.f)));
    }
    U4 fA0, fA1, fA2;
    fA0.u = make_uint4(pkbf(a0[0],a0[1]), pkbf(a0[2],a0[3]), pkbf(a0[4],a0[5]), pkbf(a0[6],a0[7]));
    fA1.u = make_uint4(pkbf(a1[0],a1[1]), pkbf(a1[2],a1[3]), pkbf(a1[4],a1[5]), pkbf(a1[6],a1[7]));
    fA2.u = make_uint4(pkbf(a2[0],a2[1]), pkbf(a2[2],a2[3]), pkbf(a2[4],a2[5]), pkbf(a2[6],a2[7]));
    U4 b0, b1, b2, b3, b4, b5;
    b0.u = B.b[0]; b1.u = B.b[1]; b2.u = B.b[2];
    b3.u = B.b[3]; b4.u = B.b[4]; b5.u = B.b[5];
    acc0 = MFMA32(fA0.s, b0.s, acc0, 0, 0, 0);
    acc1 = MFMA32(fA0.s, b1.s, acc1, 0, 0, 0);
    acc0 = MFMA32(fA1.s, b2.s, acc0, 0, 0, 0);
    acc1 = MFMA32(fA1.s, b3.s, acc1, 0, 0, 0);
    acc0 = MFMA32(fA2.s, b4.s, acc0, 0, 0, 0);
    acc1 = MFMA32(fA2.s, b5.s, acc1, 0, 0, 0);
  };

  BSet Ba, Bb;
  unsigned int Ya[5], Yb[5];
  ldB(0, Ba); ldYh(0, Ya);
  ldB(1, Bb); ldYh(1, Yb);

#pragma unroll 1
  for (int s = 0; s < 64; s += 2){
    agen_mfma(Ya, Ba);
    const int s2 = (s + 2 < 64) ? s + 2 : 63;
    ldB(s2, Ba); ldYh(s2, Ya);
    agen_mfma(Yb, Bb);
    const int s3 = (s + 3 < 64) ? s + 3 : 63;
    ldB(s3, Bb); ldYh(s3, Yb);
  }

  // ---- in-WG reduction over gq (red aliases Xf; y region untouched) ----
  __syncthreads();
  if (gq >= 2){
#pragma unroll
    for (int e = 0; e < 16; ++e){
      red[gq-2][lane][e]      = acc0[e];
      red[gq-2][lane][16 + e] = acc1[e];
    }
  }
  __syncthreads();
  if (gq < 2){
#pragma unroll
    for (int e = 0; e < 16; ++e){
      acc0[e] += red[gq][lane][e];
      acc1[e] += red[gq][lane][16 + e];
    }
  }
  __syncthreads();
  if (gq == 1){
#pragma unroll
    for (int e = 0; e < 16; ++e){
      red[0][lane][e]      = acc0[e];
      red[0][lane][16 + e] = acc1[e];
    }
  }
  __syncthreads();
  if (gq == 0){
#pragma unroll
    for (int e = 0; e < 16; ++e){
      float v0 = acc0[e] + red[0][lane][e];
      float v1 = acc1[e] + red[0][lane][16 + e];
      int rowm = (e & 3) + 8*(e >> 2) + 4*h;
      float* d = mix + (size_t)(pbase + rowm)*128 + nh*64 + pr;
      d[0]  = v0;
      d[32] = v1;
    }
  }
}

// ---------------- MLP + final einsum + epilogue ----------------
__global__ __launch_bounds__(256, 1)
void mlp_final(const float* __restrict__ x, const float* __restrict__ y,
               const ushort_t* __restrict__ whfrag,
               const ushort_t* __restrict__ wffrag,
               const float* __restrict__ mix, float* __restrict__ out){
  extern __shared__ char ldsm[];
  ushort_t* hw = (ushort_t*)ldsm;
  const int t = threadIdx.x;
  const long pbase = (long)blockIdx.x * 32;

  {  // load mix -> act buf0 (bf16)
    int p = t >> 3, n0 = (t & 7) * 16;
    const float* src = mix + (pbase + p)*128 + n0;
    int path = n0 >> 6, nn = n0 & 63;
    ushort_t* dst = hw + (path*2)*2176 + p*68 + nn;
#pragma unroll
    for (int q2 = 0; q2 < 16; ++q2) dst[q2] = f2bf(src[q2]);
  }
  __syncthreads();

  const int w = t >> 6, lane = t & 63;
  const int path = w >> 1, ntw = w & 1;
  const int prow = lane & 31, h = lane >> 5;
  int cur = 0;

#pragma unroll
  for (int layer = 0; layer < 2; ++layer){
    const ushort_t* act = hw + (path*2 + cur)*2176;
    f32x16 acc;
#pragma unroll
    for (int r = 0; r < 16; ++r) acc[r] = 0.f;
#pragma unroll
    for (int c = 0; c < 4; ++c){
      int ab = prow*68 + c*16 + 4*h;
      ushort4 lo = *(const ushort4*)&act[ab];
      ushort4 hi = *(const ushort4*)&act[ab + 8];
      short8 av; av[0]=lo.x; av[1]=lo.y; av[2]=lo.z; av[3]=lo.w;
      av[4]=hi.x; av[5]=hi.y; av[6]=hi.z; av[7]=hi.w;
      short8 bv = *(const short8*)(whfrag + ((((layer*2 + path)*4 + c)*2 + ntw)*512 + lane*8));
      acc = MFMA32(av, bv, acc, 0, 0, 0);
    }
    ushort_t* nact = hw + (path*2 + (cur ^ 1))*2176;
#pragma unroll
    for (int r = 0; r < 16; ++r){
      int p = (r & 3) + 8*(r >> 2) + 4*h;
      nact[p*68 + ntw*32 + prow] = f2bf(tanh_fast(acc[r]));
    }
    cur ^= 1;
    __syncthreads();
  }

  {  // final einsum: o[p][n=l*64+f], N=192 -> each wave 3 n-tiles
    const ushort_t* act = hw + (path*2 + cur)*2176;
    ushort_t* ob = hw + 8704 + path*6272;
#pragma unroll
    for (int e = 0; e < 3; ++e){
      int ntf = ntw*3 + e;
      f32x16 acc;
#pragma unroll
      for (int r = 0; r < 16; ++r) acc[r] = 0.f;
#pragma unroll
      for (int c = 0; c < 4; ++c){
        int ab = prow*68 + c*16 + 4*h;
        ushort4 lo = *(const ushort4*)&act[ab];
        ushort4 hi = *(const ushort4*)&act[ab + 8];
        short8 av; av[0]=lo.x; av[1]=lo.y; av[2]=lo.z; av[3]=lo.w;
        av[4]=hi.x; av[5]=hi.y; av[6]=hi.z; av[7]=hi.w;
        short8 bv = *(const short8*)(wffrag + (((path*4 + c)*6 + ntf)*512 + lane*8));
        acc = MFMA32(av, bv, acc, 0, 0, 0);
      }
#pragma unroll
      for (int r = 0; r < 16; ++r){
        int p = (r & 3) + 8*(r >> 2) + 4*h;
        ob[p*196 + ntf*32 + prow] = f2bf(tanh_fast(acc[r]));
      }
    }
  }
  __syncthreads();

  const ushort_t* oxb = hw + 8704;
  const ushort_t* oyb = hw + 8704 + 6272;
#pragma unroll 1
  for (int rep = 0; rep < 8; ++rep){
    int idx = t + rep*256;
    int p = idx >> 6, fq = idx & 63;
    const float* xr = x + ((pbase + p)*64 + fq)*9;
    const float* yr = y + ((pbase + p)*64 + fq)*9;
    float xv[9], yv[9];
#pragma unroll
    for (int s = 0; s < 9; ++s){ xv[s] = xr[s]; yv[s] = yr[s]; }
    float c0 = xv[2]*yv[3] - xv[3]*yv[2];
    float c1 = xv[3]*yv[1] - xv[1]*yv[3];
    float c2 = xv[1]*yv[2] - xv[2]*yv[1];
    float gate = c0*yv[0] + c1*yv[1] + c2*yv[2];
    float ox0 = bf2f(oxb[p*196 + fq]);
    float ox1 = bf2f(oxb[p*196 + 64 + fq]);
    float ox2 = bf2f(oxb[p*196 + 128 + fq]);
    float oy0 = bf2f(oyb[p*196 + fq]);
    float oy1 = bf2f(oyb[p*196 + 64 + fq]);
    float oy2 = bf2f(oyb[p*196 + 128 + fq]);
    float* orow = out + ((pbase + p)*64 + fq)*9;
    orow[0] = ox0*xv[0]*gate + oy0*yv[0];
#pragma unroll
    for (int s = 1; s < 4; ++s) orow[s] = ox1*xv[s]*gate + oy1*yv[s];
#pragma unroll
    for (int s = 4; s < 9; ++s) orow[s] = ox2*xv[s]*gate + oy2*yv[s];
  }
}

extern "C" void kernel_launch(void* const* d_in, const int* in_sizes, int n_in,
                              void* d_out, int out_size, void* d_ws, size_t ws_size,
                              hipStream_t stream){
  (void)in_sizes; (void)n_in; (void)out_size; (void)ws_size;
  const float* x   = (const float*)d_in[0];
  const float* y   = (const float*)d_in[1];
  const float* wx0 = (const float*)d_in[2];
  const float* wy0 = (const float*)d_in[3];
  const float* wxh = (const float*)d_in[4];
  const float* wyh = (const float*)d_in[5];
  const float* wxf = (const float*)d_in[6];
  const float* wyf = (const float*)d_in[7];
  float* out = (float*)d_out;
  char* ws = (char*)d_ws;
  ushort_t* wfrag  = (ushort_t*)(ws);              //  3,145,728 B
  ushort_t* whfrag = (ushort_t*)(ws + 3145728);    //     32,768 B
  ushort_t* wffrag = (ushort_t*)(ws + 3178496);    //     49,152 B
  float* mix       = (float*)(ws + 3227648);       //  4,194,304 B

  (void)hipFuncSetAttribute((const void*)gemm9,
        hipFuncAttributeMaxDynamicSharedMemorySize, 78720);
  (void)hipFuncSetAttribute((const void*)mlp_final,
        hipFuncAttributeMaxDynamicSharedMemorySize, 43520);

  hipLaunchKernelGGL(bake_w0, dim3(768), dim3(256), 0, stream, wx0, wy0, wfrag);
  hipLaunchKernelGGL(bake_wh, dim3(8),   dim3(256), 0, stream, wxh, wyh, whfrag);
  hipLaunchKernelGGL(bake_wf, dim3(12),  dim3(256), 0, stream, wxf, wyf, wffrag);
  hipLaunchKernelGGL(gemm9,   dim3(512), dim3(256), 78720, stream, x, y, wfrag, mix);
  hipLaunchKernelGGL(mlp_final, dim3(256), dim3(256), 42496, stream, x, y, whfrag, wffrag, mix, out);
}

// Round 10
// 90.776 us; speedup vs baseline: 1.4930x; 1.0102x over previous
//
#include <hip/hip_runtime.h>
#include <hip/hip_bf16.h>

typedef __attribute__((ext_vector_type(8))) short short8;
typedef __attribute__((ext_vector_type(16))) float f32x16;
typedef __fp16 h2 __attribute__((ext_vector_type(2)));
typedef unsigned short ushort_t;

#define DEVFN static __device__ __forceinline__
#define MFMA32 __builtin_amdgcn_mfma_f32_32x32x16_bf16

DEVFN float bf2f(unsigned short u){
  union { unsigned int i; float f; } v; v.i = ((unsigned int)u) << 16; return v.f;
}
DEVFN unsigned short f2bf(float f){
  unsigned int u = __float_as_uint(f);
  unsigned int r = u + 0x7FFFu + ((u >> 16) & 1u);
  return (unsigned short)(r >> 16);
}
// HW packed f32x2 -> bf16x2 (low = first arg); no builtin on gfx950 -> inline asm
DEVFN unsigned int pkbf(float a, float b){
  unsigned int r;
  asm("v_cvt_pk_bf16_f32 %0, %1, %2" : "=v"(r) : "v"(a), "v"(b));
  return r;
}
DEVFN h2 pkrtz(float a, float b){ return __builtin_amdgcn_cvt_pkrtz(a, b); }
DEVFN h2 u2h(unsigned int u){ union { unsigned int u; h2 h; } v; v.u = u; return v.h; }
#if __has_builtin(__builtin_amdgcn_fdot2)
DEVFN float fdot2(h2 a, h2 b, float c){ return __builtin_amdgcn_fdot2(a, b, c, false); }
#else
DEVFN float fdot2(h2 a, h2 b, float c){ return c + (float)a[0]*(float)b[0] + (float)a[1]*(float)b[1]; }
#endif
DEVFN float tanh_fast(float x){
  float t = __builtin_amdgcn_exp2f(x * 2.885390081777926815f);
  return 1.0f - 2.0f * __builtin_amdgcn_rcpf(t + 1.0f);
}
// shared A/B K-slot mapping for 32x32x16 MFMA fragments
DEVFN int kmap(int h, int j){ return 4*h + (j & 3) + 8*(j >> 2); }

// ---------------- weight bake (coalesced reads, scattered stores) ----------------
// wfrag (hw): ((f*4 + gq)*2 + nh)*3072 + (l*2 + nt)*512 + lane*8 + j
// inverse map: g -> gq=g>>4, gl=g&15, h=(gl>>2)&1, j=(gl&3)|((gl>>3)<<2)
__global__ void bake_w0(const float* __restrict__ wx0, const float* __restrict__ wy0,
                        ushort_t* __restrict__ wfrag){
  int idx = blockIdx.x * 256 + threadIdx.x;   // < 524288
  int g = idx & 63; int r = idx >> 6;
  int f = r & 63; r >>= 6;
  int k = r & 63; int path = r >> 6;
  const float* w = path ? wy0 : wx0;
  const float* src = w + ((size_t)(k*64 + f)*64 + g)*3;
  float v0 = src[0], v1 = src[1], v2 = src[2];      // coalesced (12B stride over g)
  int gq = g >> 4, gl = g & 15;
  int h = (gl >> 2) & 1;
  int j = (gl & 3) | ((gl >> 3) << 2);
  int lane = h*32 + (k & 31);
  int nt = k >> 5;
  size_t base = (size_t)((f*4 + gq)*2 + path)*3072 + (size_t)lane*8 + j;
  wfrag[base + 0*512 + (size_t)nt*512] = f2bf(v0);           // l=0
  wfrag[base + 2*512 + (size_t)nt*512] = f2bf(v1);           // l=1
  wfrag[base + 4*512 + (size_t)nt*512] = f2bf(v2);           // l=2
}

__global__ void bake_wh(const float* __restrict__ wxh, const float* __restrict__ wyh,
                        ushort_t* __restrict__ whfrag){
  int slot = blockIdx.x * 256 + threadIdx.x;      // < 2048
  int lane = slot & 63;
  int q = slot >> 6;
  int nt = q & 1; q >>= 1;
  int c  = q & 3; q >>= 2;
  int path = q & 1; int layer = q >> 1;
  const float* w = path ? wyh : wxh;
  int n = nt*32 + (lane & 31);
  int h = lane >> 5;
  unsigned int pk[4];
#pragma unroll
  for (int jj = 0; jj < 4; ++jj){
    int k0 = c*16 + kmap(h, 2*jj);
    int k1 = c*16 + kmap(h, 2*jj + 1);
    unsigned int b0 = f2bf(w[layer*4096 + k0*64 + n]);
    unsigned int b1 = f2bf(w[layer*4096 + k1*64 + n]);
    pk[jj] = b0 | (b1 << 16);
  }
  *reinterpret_cast<uint4*>(whfrag + (size_t)slot * 8) = make_uint4(pk[0], pk[1], pk[2], pk[3]);
}

__global__ void bake_wf(const float* __restrict__ wxf, const float* __restrict__ wyf,
                        ushort_t* __restrict__ wffrag){
  int slot = blockIdx.x * 256 + threadIdx.x;      // < 3072
  int lane = slot & 63;
  int q = slot >> 6;            // < 48
  int ntf = q % 6;
  int q2 = q / 6;
  int c = q2 & 3; int path = q2 >> 2;
  const float* w = path ? wyf : wxf;
  int n = ntf*32 + (lane & 31);
  int lw = n >> 6, fw = n & 63;
  int h = lane >> 5;
  unsigned int pk[4];
#pragma unroll
  for (int jj = 0; jj < 4; ++jj){
    int k0 = c*16 + kmap(h, 2*jj);
    int k1 = c*16 + kmap(h, 2*jj + 1);
    unsigned int b0 = f2bf(w[(lw*64 + fw)*64 + k0]);
    unsigned int b1 = f2bf(w[(lw*64 + fw)*64 + k1]);
    pk[jj] = b0 | (b1 << 16);
  }
  *reinterpret_cast<uint4*>(wffrag + (size_t)slot * 8) = make_uint4(pk[0], pk[1], pk[2], pk[3]);
}

// ---------------- main fused GEMM ----------------
// Grid 512 = Mblk(256, 32 pts) x nh(2); WG 256 thr = 4 waves = gq quarters.
// LDS: YH f16 [32 p][325 dwords] @0 (41600 B) ; red [64][33] f32 @41600 (8448 B)
// Total 50048 B -> 3 WG/CU (vs round 9's 78.7KB -> 2).
// Loop: coalesced B stream (regs) + LDS Y + HW cvt_pk_bf16; barrier-free.
struct BSet { uint4 b[6]; };
union U4 { uint4 u; short8 s; };

__global__ __launch_bounds__(256)
void gemm10(const float* __restrict__ x, const float* __restrict__ y,
            const ushort_t* __restrict__ wfrag, float* __restrict__ mix){
  extern __shared__ char lds[];
  unsigned int* YHd = (unsigned int*)lds;                 // [32][325] dwords
  ushort_t* YHh = (ushort_t*)lds;
  float (*red)[33] = (float (*)[33])(lds + 41600);        // [64][33]

  const int bid = blockIdx.x;
  const int id = (bid & 7)*64 + (bid >> 3);               // XCD-chunked bijection
  const int nh = id & 1, mb = id >> 1;
  const int pbase = mb * 32;

  const int t = threadIdx.x, lane = t & 63, gq = t >> 6;
  const int h = lane >> 5, pr = lane & 31;

  const float* yb = y + (size_t)pbase * 576;

  // ---- stage y as f16 into LDS (coalesced float4 reads) ----
#pragma unroll
  for (int c = 0; c < 18; ++c){
    int q = t + c*256;                 // < 4608
    int p = q / 144, off = (q - p*144) * 4;
    float4 v = *(const float4*)(yb + p*576 + off);
#pragma unroll
    for (int i = 0; i < 4; ++i){
      int flat = off + i;
      int f = flat / 9, s = flat - f*9;
      float vv = (i==0) ? v.x : (i==1) ? v.y : (i==2) ? v.z : v.w;
      union { __fp16 hf; ushort_t u; } cv; cv.hf = (__fp16)vv;
      YHh[p*650 + f*10 + s] = cv.u;
    }
  }
  __syncthreads();

  // ---- xg init: x via per-lane scalar loads (one-time), y from LDS ----
  h2 xg[8][5];
#pragma unroll
  for (int j = 0; j < 8; ++j){
    const int g = gq*16 + kmap(h, j);
    const float* xp = x + (size_t)(pbase + pr)*576 + g*9;
    unsigned int yd0 = YHd[pr*325 + g*5 + 0];
    unsigned int yd1 = YHd[pr*325 + g*5 + 1];
    h2 y01 = u2h(yd0), y23v = u2h(yd1);
    float y0 = (float)y01[0], y1 = (float)y01[1];
    float y2 = (float)y23v[0], y3 = (float)y23v[1];
    float x1 = xp[1], x2 = xp[2], x3 = xp[3];
    float gate = (x2*y3 - x3*y2)*y0 + (x3*y1 - x1*y3)*y1 + (x1*y2 - x2*y1)*y2;
    xg[j][0] = pkrtz(xp[0]*gate, x1*gate);
    xg[j][1] = pkrtz(x2*gate, x3*gate);
    xg[j][2] = pkrtz(xp[4]*gate, xp[5]*gate);
    xg[j][3] = pkrtz(xp[6]*gate, xp[7]*gate);
    xg[j][4] = pkrtz(xp[8]*gate, 0.f);
  }

  // ---- main loop ----
  f32x16 acc0, acc1;
#pragma unroll
  for (int e = 0; e < 16; ++e){ acc0[e] = 0.f; acc1[e] = 0.f; }

  const ushort_t* wt = wfrag + (size_t)(gq*2 + nh)*3072 + (size_t)lane*8;
  const unsigned int* yrow = YHd + pr*325;

  auto ldB = [&](int f, BSet& B){
    const ushort_t* p0 = wt + (size_t)f * 24576;
#pragma unroll
    for (int i = 0; i < 6; ++i) B.b[i] = *reinterpret_cast<const uint4*>(p0 + i*512);
  };
  auto ldYh = [&](int f, unsigned int* Yr){
#pragma unroll
    for (int d = 0; d < 5; ++d) Yr[d] = yrow[f*5 + d];
  };
  auto agen_mfma = [&](const unsigned int* Yr, const BSet& B){
    h2 y0m = u2h(Yr[0] & 0xFFFFu);
    h2 y1m = u2h(Yr[0] & 0xFFFF0000u);
    h2 y23 = u2h(Yr[1]), y45 = u2h(Yr[2]), y67 = u2h(Yr[3]);
    h2 y8p = u2h(Yr[4] & 0xFFFFu);
    float a0[8], a1[8], a2[8];
#pragma unroll
    for (int j = 0; j < 8; ++j){
      a0[j] = fdot2(xg[j][0], y0m, 0.f);
      a1[j] = fdot2(xg[j][1], y23, fdot2(xg[j][0], y1m, 0.f));
      a2[j] = fdot2(xg[j][4], y8p, fdot2(xg[j][3], y67, fdot2(xg[j][2], y45, 0.f)));
    }
    U4 fA0, fA1, fA2;
    fA0.u = make_uint4(pkbf(a0[0],a0[1]), pkbf(a0[2],a0[3]), pkbf(a0[4],a0[5]), pkbf(a0[6],a0[7]));
    fA1.u = make_uint4(pkbf(a1[0],a1[1]), pkbf(a1[2],a1[3]), pkbf(a1[4],a1[5]), pkbf(a1[6],a1[7]));
    fA2.u = make_uint4(pkbf(a2[0],a2[1]), pkbf(a2[2],a2[3]), pkbf(a2[4],a2[5]), pkbf(a2[6],a2[7]));
    U4 b0, b1, b2, b3, b4, b5;
    b0.u = B.b[0]; b1.u = B.b[1]; b2.u = B.b[2];
    b3.u = B.b[3]; b4.u = B.b[4]; b5.u = B.b[5];
    acc0 = MFMA32(fA0.s, b0.s, acc0, 0, 0, 0);
    acc1 = MFMA32(fA0.s, b1.s, acc1, 0, 0, 0);
    acc0 = MFMA32(fA1.s, b2.s, acc0, 0, 0, 0);
    acc1 = MFMA32(fA1.s, b3.s, acc1, 0, 0, 0);
    acc0 = MFMA32(fA2.s, b4.s, acc0, 0, 0, 0);
    acc1 = MFMA32(fA2.s, b5.s, acc1, 0, 0, 0);
  };

  BSet Ba, Bb;
  unsigned int Ya[5], Yb[5];
  ldB(0, Ba); ldYh(0, Ya);
  ldB(1, Bb); ldYh(1, Yb);

#pragma unroll 1
  for (int s = 0; s < 64; s += 2){
    agen_mfma(Ya, Ba);
    const int s2 = (s + 2 < 64) ? s + 2 : 63;
    ldB(s2, Ba); ldYh(s2, Ya);
    agen_mfma(Yb, Bb);
    const int s3 = (s + 3 < 64) ? s + 3 : 63;
    ldB(s3, Bb); ldYh(s3, Yb);
  }

  // ---- in-WG reduction over gq (serialized through one 8.4KB buffer) ----
  __syncthreads();
#pragma unroll 1
  for (int rr = 1; rr <= 3; ++rr){
    if (gq == rr){
#pragma unroll
      for (int e = 0; e < 16; ++e){
        red[lane][e]      = acc0[e];
        red[lane][16 + e] = acc1[e];
      }
    }
    __syncthreads();
    if (gq == 0){
#pragma unroll
      for (int e = 0; e < 16; ++e){
        acc0[e] += red[lane][e];
        acc1[e] += red[lane][16 + e];
      }
    }
    __syncthreads();
  }
  if (gq == 0){
#pragma unroll
    for (int e = 0; e < 16; ++e){
      int rowm = (e & 3) + 8*(e >> 2) + 4*h;
      float* d = mix + (size_t)(pbase + rowm)*128 + nh*64 + pr;
      d[0]  = acc0[e];
      d[32] = acc1[e];
    }
  }
}

// ---------------- MLP + final einsum + epilogue ----------------
__global__ __launch_bounds__(256, 1)
void mlp_final(const float* __restrict__ x, const float* __restrict__ y,
               const ushort_t* __restrict__ whfrag,
               const ushort_t* __restrict__ wffrag,
               const float* __restrict__ mix, float* __restrict__ out){
  extern __shared__ char ldsm[];
  ushort_t* hw = (ushort_t*)ldsm;
  const int t = threadIdx.x;
  const long pbase = (long)blockIdx.x * 32;

  {  // load mix -> act buf0 (bf16)
    int p = t >> 3, n0 = (t & 7) * 16;
    const float* src = mix + (pbase + p)*128 + n0;
    int path = n0 >> 6, nn = n0 & 63;
    ushort_t* dst = hw + (path*2)*2176 + p*68 + nn;
#pragma unroll
    for (int q2 = 0; q2 < 16; ++q2) dst[q2] = f2bf(src[q2]);
  }
  __syncthreads();

  const int w = t >> 6, lane = t & 63;
  const int path = w >> 1, ntw = w & 1;
  const int prow = lane & 31, h = lane >> 5;
  int cur = 0;

#pragma unroll
  for (int layer = 0; layer < 2; ++layer){
    const ushort_t* act = hw + (path*2 + cur)*2176;
    f32x16 acc;
#pragma unroll
    for (int r = 0; r < 16; ++r) acc[r] = 0.f;
#pragma unroll
    for (int c = 0; c < 4; ++c){
      int ab = prow*68 + c*16 + 4*h;
      ushort4 lo = *(const ushort4*)&act[ab];
      ushort4 hi = *(const ushort4*)&act[ab + 8];
      short8 av; av[0]=lo.x; av[1]=lo.y; av[2]=lo.z; av[3]=lo.w;
      av[4]=hi.x; av[5]=hi.y; av[6]=hi.z; av[7]=hi.w;
      short8 bv = *(const short8*)(whfrag + ((((layer*2 + path)*4 + c)*2 + ntw)*512 + lane*8));
      acc = MFMA32(av, bv, acc, 0, 0, 0);
    }
    ushort_t* nact = hw + (path*2 + (cur ^ 1))*2176;
#pragma unroll
    for (int r = 0; r < 16; ++r){
      int p = (r & 3) + 8*(r >> 2) + 4*h;
      nact[p*68 + ntw*32 + prow] = f2bf(tanh_fast(acc[r]));
    }
    cur ^= 1;
    __syncthreads();
  }

  {  // final einsum: o[p][n=l*64+f], N=192 -> each wave 3 n-tiles
    const ushort_t* act = hw + (path*2 + cur)*2176;
    ushort_t* ob = hw + 8704 + path*6272;
#pragma unroll
    for (int e = 0; e < 3; ++e){
      int ntf = ntw*3 + e;
      f32x16 acc;
#pragma unroll
      for (int r = 0; r < 16; ++r) acc[r] = 0.f;
#pragma unroll
      for (int c = 0; c < 4; ++c){
        int ab = prow*68 + c*16 + 4*h;
        ushort4 lo = *(const ushort4*)&act[ab];
        ushort4 hi = *(const ushort4*)&act[ab + 8];
        short8 av; av[0]=lo.x; av[1]=lo.y; av[2]=lo.z; av[3]=lo.w;
        av[4]=hi.x; av[5]=hi.y; av[6]=hi.z; av[7]=hi.w;
        short8 bv = *(const short8*)(wffrag + (((path*4 + c)*6 + ntf)*512 + lane*8));
        acc = MFMA32(av, bv, acc, 0, 0, 0);
      }
#pragma unroll
      for (int r = 0; r < 16; ++r){
        int p = (r & 3) + 8*(r >> 2) + 4*h;
        ob[p*196 + ntf*32 + prow] = f2bf(tanh_fast(acc[r]));
      }
    }
  }
  __syncthreads();

  const ushort_t* oxb = hw + 8704;
  const ushort_t* oyb = hw + 8704 + 6272;
#pragma unroll 1
  for (int rep = 0; rep < 8; ++rep){
    int idx = t + rep*256;
    int p = idx >> 6, fq = idx & 63;
    const float* xr = x + ((pbase + p)*64 + fq)*9;
    const float* yr = y + ((pbase + p)*64 + fq)*9;
    float xv[9], yv[9];
#pragma unroll
    for (int s = 0; s < 9; ++s){ xv[s] = xr[s]; yv[s] = yr[s]; }
    float c0 = xv[2]*yv[3] - xv[3]*yv[2];
    float c1 = xv[3]*yv[1] - xv[1]*yv[3];
    float c2 = xv[1]*yv[2] - xv[2]*yv[1];
    float gate = c0*yv[0] + c1*yv[1] + c2*yv[2];
    float ox0 = bf2f(oxb[p*196 + fq]);
    float ox1 = bf2f(oxb[p*196 + 64 + fq]);
    float ox2 = bf2f(oxb[p*196 + 128 + fq]);
    float oy0 = bf2f(oyb[p*196 + fq]);
    float oy1 = bf2f(oyb[p*196 + 64 + fq]);
    float oy2 = bf2f(oyb[p*196 + 128 + fq]);
    float* orow = out + ((pbase + p)*64 + fq)*9;
    orow[0] = ox0*xv[0]*gate + oy0*yv[0];
#pragma unroll
    for (int s = 1; s < 4; ++s) orow[s] = ox1*xv[s]*gate + oy1*yv[s];
#pragma unroll
    for (int s = 4; s < 9; ++s) orow[s] = ox2*xv[s]*gate + oy2*yv[s];
  }
}

extern "C" void kernel_launch(void* const* d_in, const int* in_sizes, int n_in,
                              void* d_out, int out_size, void* d_ws, size_t ws_size,
                              hipStream_t stream){
  (void)in_sizes; (void)n_in; (void)out_size; (void)ws_size;
  const float* x   = (const float*)d_in[0];
  const float* y   = (const float*)d_in[1];
  const float* wx0 = (const float*)d_in[2];
  const float* wy0 = (const float*)d_in[3];
  const float* wxh = (const float*)d_in[4];
  const float* wyh = (const float*)d_in[5];
  const float* wxf = (const float*)d_in[6];
  const float* wyf = (const float*)d_in[7];
  float* out = (float*)d_out;
  char* ws = (char*)d_ws;
  ushort_t* wfrag  = (ushort_t*)(ws);              //  3,145,728 B
  ushort_t* whfrag = (ushort_t*)(ws + 3145728);    //     32,768 B
  ushort_t* wffrag = (ushort_t*)(ws + 3178496);    //     49,152 B
  float* mix       = (float*)(ws + 3227648);       //  4,194,304 B

  (void)hipFuncSetAttribute((const void*)gemm10,
        hipFuncAttributeMaxDynamicSharedMemorySize, 50048);
  (void)hipFuncSetAttribute((const void*)mlp_final,
        hipFuncAttributeMaxDynamicSharedMemorySize, 43520);

  hipLaunchKernelGGL(bake_w0, dim3(2048), dim3(256), 0, stream, wx0, wy0, wfrag);
  hipLaunchKernelGGL(bake_wh, dim3(8),    dim3(256), 0, stream, wxh, wyh, whfrag);
  hipLaunchKernelGGL(bake_wf, dim3(12),   dim3(256), 0, stream, wxf, wyf, wffrag);
  hipLaunchKernelGGL(gemm10,  dim3(512),  dim3(256), 50048, stream, x, y, wfrag, mix);
  hipLaunchKernelGGL(mlp_final, dim3(256), dim3(256), 42496, stream, x, y, whfrag, wffrag, mix, out);
}